// Round 3
// baseline (256.428 us; speedup 1.0000x reference)
//
#include <hip/hip_runtime.h>

#define NN 10000      // nodes (also the zero pad-row index)

typedef __attribute__((ext_vector_type(8))) short short8;
typedef __attribute__((ext_vector_type(4))) float f32x4;

__device__ __forceinline__ ushort f2b(float f) {
    union { float f; uint32_t u; } v; v.f = f;
    uint32_t u = v.u;
    return (ushort)((u + 0x7fffu + ((u >> 16) & 1u)) >> 16);
}
__device__ __forceinline__ uint packbf(float a, float b) {
    return (uint)f2b(a) | ((uint)f2b(b) << 16);
}
__device__ __forceinline__ float blo(uint u) {
    union { uint u; float f; } v; v.u = u << 16; return v.f;
}
__device__ __forceinline__ float bhi(uint u) {
    union { uint u; float f; } v; v.u = u & 0xffff0000u; return v.f;
}

// ---------------------------------------------------------------------------
// CSR build kernels. NEW: edge lists padded to multiples of 8 with the
// zero-row index NN, so the aggregation loop has no scalar tail. Padding
// with exact zeros leaves the segment sum bitwise identical (mean divides
// by the TRUE count).
// ---------------------------------------------------------------------------
__global__ __launch_bounds__(256) void zero_int(int* __restrict__ p, int n) {
    int i = blockIdx.x * 256 + threadIdx.x;
    if (i < n) p[i] = 0;
}

__global__ __launch_bounds__(256) void count_dst(const int* __restrict__ dst,
                                                 int* __restrict__ counts, int E) {
    int i = blockIdx.x * 256 + threadIdx.x;
    if (i < E) atomicAdd(&counts[dst[i]], 1);
}

__global__ __launch_bounds__(1024) void scan_build(const int* __restrict__ counts,
                                                   int* __restrict__ offsets,
                                                   int* __restrict__ cursor,
                                                   float* __restrict__ inv_cnt,
                                                   int* __restrict__ sorted_src, int n) {
    __shared__ int part[1024];
    int tid = threadIdx.x;
    int per = (n + 1023) / 1024;
    int base = tid * per;
    int s = 0;
    for (int i = 0; i < per; i++) {
        int idx = base + i;
        if (idx < n) s += (counts[idx] + 7) & ~7;   // padded sizes
    }
    part[tid] = s;
    __syncthreads();
    for (int off = 1; off < 1024; off <<= 1) {
        int v = (tid >= off) ? part[tid - off] : 0;
        __syncthreads();
        part[tid] += v;
        __syncthreads();
    }
    int run = (tid > 0) ? part[tid - 1] : 0;
    for (int i = 0; i < per; i++) {
        int idx = base + i;
        if (idx < n) {
            int c    = counts[idx];
            int cpad = (c + 7) & ~7;
            offsets[idx] = run;
            cursor[idx]  = run;
            inv_cnt[idx] = 1.0f / fmaxf((float)c, 1.0f);
            for (int j = c; j < cpad; j++) sorted_src[run + j] = NN;  // pad slots
            run += cpad;
        }
    }
}

__global__ __launch_bounds__(256) void scatter_edges(const int* __restrict__ src,
                                                     const int* __restrict__ dst,
                                                     int* __restrict__ cursor,
                                                     int* __restrict__ sorted_src, int E) {
    int i = blockIdx.x * 256 + threadIdx.x;
    if (i < E) {
        int p = atomicAdd(&cursor[dst[i]], 1);
        sorted_src[p] = src[i];
    }
}

// ---------------------------------------------------------------------------
// Single fused fp32->bf16 conversion kernel + pad-row zeroing.
// Ranges in 4-float groups:
//   x:  [0, 1280000)          -> xbuf  (linear)
//   W0: [1280000, 1411072)    -> Wc0   (dout=512)
//   W1: [1411072, 1542144)    -> Wc1   (dout=512)
//   W2: [1542144, 1607680)    -> Wc2   (dout=256)
//   [1607680, 1607744): zero Gbuf pad row (512 ushorts, 64 thr x 8)
//   [1607744, 1607776): zero G2  pad row (256 ushorts, 32 thr x 8)
// ---------------------------------------------------------------------------
__global__ __launch_bounds__(256) void cvt_all(const float* __restrict__ x,
                                               const float* __restrict__ Wl0,
                                               const float* __restrict__ Wr0,
                                               const float* __restrict__ Wl1,
                                               const float* __restrict__ Wr1,
                                               const float* __restrict__ Wl2,
                                               const float* __restrict__ Wr2,
                                               ushort* __restrict__ xbuf,
                                               ushort* __restrict__ Wc0,
                                               ushort* __restrict__ Wc1,
                                               ushort* __restrict__ Wc2,
                                               ushort* __restrict__ Gbuf,
                                               ushort* __restrict__ G2) {
    int i = blockIdx.x * 256 + threadIdx.x;
    const float* src;
    ushort* dst;
    if (i < 1280000) {
        int idx = i * 4;
        src = x + idx;
        dst = xbuf + idx;
    } else if (i < 1411072) {
        int j = (i - 1280000) * 4;
        int row = j >> 9, col = j & 511;
        src = (row < 512) ? (Wl0 + (size_t)row * 512 + col)
                          : (Wr0 + (size_t)(row - 512) * 512 + col);
        dst = Wc0 + j;
    } else if (i < 1542144) {
        int j = (i - 1411072) * 4;
        int row = j >> 9, col = j & 511;
        src = (row < 512) ? (Wl1 + (size_t)row * 512 + col)
                          : (Wr1 + (size_t)(row - 512) * 512 + col);
        dst = Wc1 + j;
    } else if (i < 1607680) {
        int j = (i - 1542144) * 4;
        int row = j >> 9, col = j & 511;
        src = (row < 256) ? (Wl2 + (size_t)row * 512 + col)
                          : (Wr2 + (size_t)(row - 256) * 512 + col);
        dst = Wc2 + j;
    } else if (i < 1607744) {
        int t = i - 1607680;
        uint4 z = {0, 0, 0, 0};
        *(uint4*)(Gbuf + (size_t)NN * 512 + t * 8) = z;
        return;
    } else if (i < 1607776) {
        int t = i - 1607744;
        uint4 z = {0, 0, 0, 0};
        *(uint4*)(G2 + (size_t)NN * 256 + t * 8) = z;
        return;
    } else {
        return;
    }
    float4 v = *(const float4*)src;
    uint2 p;
    p.x = packbf(v.x, v.y);
    p.y = packbf(v.z, v.w);
    *(uint2*)dst = p;
}

// ---------------------------------------------------------------------------
// bf16 MFMA NT-GEMM, split output (byte-identical structure to R2).
// ---------------------------------------------------------------------------
__global__ __launch_bounds__(256) void gemm_split(const ushort* __restrict__ A,
                                                  const ushort* __restrict__ B,
                                                  ushort* __restrict__ G,
                                                  float* __restrict__ R,
                                                  int M, int dout) {
    __shared__ ushort Asl[2][128 * 32];   // 16 KB
    __shared__ ushort Bsl[2][128 * 32];   // 16 KB
    const int tid  = threadIdx.x;
    const int w    = tid >> 6;
    const int lane = tid & 63;

    // --- bijective XCD-chunked swizzle (nwg may not be a multiple of 8) ---
    const int nbx = gridDim.x, nby = gridDim.y;
    const int nwg = nbx * nby;
    const int id  = blockIdx.y * nbx + blockIdx.x;
    const int qq  = nwg >> 3, rr = nwg & 7;
    const int xcd = id & 7, blk = id >> 3;
    const int swzid = (xcd < rr ? xcd * (qq + 1) : rr * (qq + 1) + (xcd - rr) * qq) + blk;
    const int bx = swzid % nbx, by = swzid / nbx;

    const int bm = by * 128, bn = bx * 128;
    const int wm = (w & 1) * 64, wn = (w >> 1) * 64;
    const int row16 = lane & 15, q = lane >> 4;

    f32x4 acc[4][4];
#pragma unroll
    for (int i = 0; i < 4; i++)
#pragma unroll
        for (int j = 0; j < 4; j++) acc[i][j] = (f32x4){0.f, 0.f, 0.f, 0.f};

    const int sc_r = lane >> 2;                  // row within 16-row chunk
    const int sc_s = lane & 3;                   // physical 16B slot
    const int koff = sc_s ^ ((sc_r >> 1) & 3);   // logical k-chunk in this slot
    const int swz  = (row16 >> 1) & 3;

    auto stage = [&](int buf, int k0) {
#pragma unroll
        for (int c = 0; c < 2; c++) {
            int chunk = w * 2 + c;
            int rloc  = chunk * 16 + sc_r;
            int growA = bm + rloc; growA = growA < M ? growA : M - 1;
            const ushort* gpA = A + (size_t)growA * 512 + k0 + koff * 8;
            __builtin_amdgcn_global_load_lds(
                (const __attribute__((address_space(1))) uint32_t*)gpA,
                (__attribute__((address_space(3))) uint32_t*)&Asl[buf][chunk * 512],
                16, 0, 0);
            const ushort* gpB = B + (size_t)(bn + rloc) * 512 + k0 + koff * 8;
            __builtin_amdgcn_global_load_lds(
                (const __attribute__((address_space(1))) uint32_t*)gpB,
                (__attribute__((address_space(3))) uint32_t*)&Bsl[buf][chunk * 512],
                16, 0, 0);
        }
    };

    const int NT = 512 / 32;   // 16 K-steps
    stage(0, 0);
    __syncthreads();
    int cur = 0;

    for (int t = 0; t < NT; ++t) {
        if (t + 1 < NT) stage(cur ^ 1, (t + 1) * 32);

        short8 af[4], bfr[4];
        int s = q ^ swz;
#pragma unroll
        for (int i = 0; i < 4; i++) {
            int r = wm + i * 16 + row16;
            af[i] = *(const short8*)&Asl[cur][r * 32 + s * 8];
        }
#pragma unroll
        for (int j = 0; j < 4; j++) {
            int rn = wn + j * 16 + row16;
            bfr[j] = *(const short8*)&Bsl[cur][rn * 32 + s * 8];
        }
#pragma unroll
        for (int i = 0; i < 4; i++)
#pragma unroll
            for (int j = 0; j < 4; j++)
                acc[i][j] = __builtin_amdgcn_mfma_f32_16x16x32_bf16(
                    af[i], bfr[j], acc[i][j], 0, 0, 0);

        __syncthreads();
        cur ^= 1;
    }

    // C/D layout: col = lane&15, row = (lane>>4)*4 + reg  [m89-verified]
    const bool isR = (bn >= dout);
#pragma unroll
    for (int i = 0; i < 4; i++) {
#pragma unroll
        for (int r2 = 0; r2 < 4; r2++) {
            int row = bm + wm + i * 16 + q * 4 + r2;
            if (row < M) {
                if (isR) {
                    float* Rp = R + (size_t)row * dout + (bn - dout) + wn + row16;
#pragma unroll
                    for (int j = 0; j < 4; j++)
                        Rp[j * 16] = acc[i][j][r2];
                } else {
                    ushort* Gp = G + (size_t)row * dout + bn + wn + row16;
#pragma unroll
                    for (int j = 0; j < 4; j++)
                        Gp[j * 16] = f2b(acc[i][j][r2]);
                }
            }
        }
    }
}

// ---------------------------------------------------------------------------
// Fused neighbor mean + R + bias + L2-normalize + ReLU.
// NEW: ping-pong software-pipelined gather (two named 8-deep batches, all
// compile-time indices), no scalar tail (CSR is 8-padded with zero rows),
// R/bias issued before the gather loop.
// ---------------------------------------------------------------------------
template <int DOUT, bool FINAL>
__global__ __launch_bounds__(256) void aggfin(const ushort* __restrict__ G,
                                              const float* __restrict__ R,
                                              const float* __restrict__ bias,
                                              const int* __restrict__ offsets,
                                              const int* __restrict__ counts,
                                              const int* __restrict__ sorted_src,
                                              const float* __restrict__ inv_cnt,
                                              ushort* __restrict__ xnext,
                                              float* __restrict__ outf, int n) {
    constexpr int PL = DOUT / 64;    // floats per lane: 8 (512) or 4 (256)
    int wave = threadIdx.x >> 6;
    int lane = threadIdx.x & 63;
    int node = blockIdx.x * 4 + wave;
    if (node >= n) return;
    int start = offsets[node];
    int cnt   = counts[node];
    float inv = inv_cnt[node];
    int nb    = ((cnt + 7) & ~7) >> 3;    // full 8-batches (padded)

    // early independent loads: R + bias (HBM latency hides under gather)
    float rv[PL], bv[PL];
    {
        const float* Rp = R + (size_t)node * DOUT + lane * PL;
        const float* Bp = bias + lane * PL;
#pragma unroll
        for (int k = 0; k < PL; k += 4) {
            float4 r4 = *(const float4*)(Rp + k);
            float4 b4 = *(const float4*)(Bp + k);
            rv[k + 0] = r4.x; rv[k + 1] = r4.y; rv[k + 2] = r4.z; rv[k + 3] = r4.w;
            bv[k + 0] = b4.x; bv[k + 1] = b4.y; bv[k + 2] = b4.z; bv[k + 3] = b4.w;
        }
    }

    float acc[PL];
#pragma unroll
    for (int k = 0; k < PL; k++) acc[k] = 0.f;

    if constexpr (DOUT == 512) {
        const uint* gp = (const uint*)G + lane * 4;   // row stride 256 uints
        uint4 va[8], vb[8];
        auto load8 = [&](uint4* v, int e0) {
#pragma unroll
            for (int u = 0; u < 8; u++) {
                int s0 = sorted_src[start + e0 + u];
                v[u] = *(const uint4*)(gp + (size_t)s0 * 256);
            }
        };
#define ACC8(v) do { \
        acc[0] += blo(v.x); acc[1] += bhi(v.x); \
        acc[2] += blo(v.y); acc[3] += bhi(v.y); \
        acc[4] += blo(v.z); acc[5] += bhi(v.z); \
        acc[6] += blo(v.w); acc[7] += bhi(v.w); } while (0)
        auto acc8v = [&](const uint4* v) {
#pragma unroll
            for (int u = 0; u < 8; u++) ACC8(v[u]);
        };
#undef ACC8
        if (nb > 0) load8(va, 0);
        int b = 1;
        for (; b + 1 < nb; b += 2) {
            load8(vb, b * 8);
            acc8v(va);
            load8(va, (b + 1) * 8);
            acc8v(vb);
        }
        if (b < nb) {
            load8(vb, b * 8);
            acc8v(va);
            acc8v(vb);
        } else if (nb > 0) {
            acc8v(va);
        }
    } else {
        const uint* gp = (const uint*)G + lane * 2;   // row stride 128 uints
        uint2 va[8], vb[8];
        auto load8 = [&](uint2* v, int e0) {
#pragma unroll
            for (int u = 0; u < 8; u++) {
                int s0 = sorted_src[start + e0 + u];
                v[u] = *(const uint2*)(gp + (size_t)s0 * 128);
            }
        };
#define ACC4(v) do { \
        acc[0] += blo(v.x); acc[1] += bhi(v.x); \
        acc[2] += blo(v.y); acc[3] += bhi(v.y); } while (0)
        auto acc8v = [&](const uint2* v) {
#pragma unroll
            for (int u = 0; u < 8; u++) ACC4(v[u]);
        };
#undef ACC4
        if (nb > 0) load8(va, 0);
        int b = 1;
        for (; b + 1 < nb; b += 2) {
            load8(vb, b * 8);
            acc8v(va);
            load8(va, (b + 1) * 8);
            acc8v(vb);
        }
        if (b < nb) {
            load8(vb, b * 8);
            acc8v(va);
            acc8v(vb);
        } else if (nb > 0) {
            acc8v(va);
        }
    }

    float v[PL];
#pragma unroll
    for (int k = 0; k < PL; k++) v[k] = acc[k] * inv + rv[k] + bv[k];

    float ss = 0.f;
#pragma unroll
    for (int k = 0; k < PL; k++) ss += v[k] * v[k];
#pragma unroll
    for (int m = 32; m >= 1; m >>= 1) ss += __shfl_xor(ss, m, 64);
    float scale = 1.0f / fmaxf(sqrtf(ss), 1e-12f);

    if constexpr (FINAL) {
        float* Op = outf + (size_t)node * DOUT + lane * PL;
#pragma unroll
        for (int k = 0; k < PL; k += 4) {
            float4 o;
            o.x = fmaxf(v[k + 0] * scale, 0.f);
            o.y = fmaxf(v[k + 1] * scale, 0.f);
            o.z = fmaxf(v[k + 2] * scale, 0.f);
            o.w = fmaxf(v[k + 3] * scale, 0.f);
            *(float4*)(Op + k) = o;
        }
    } else {
        // DOUT == 512: 8 bf16 = 16B per lane
        uint4 o;
        float r0 = fmaxf(v[0] * scale, 0.f), r1 = fmaxf(v[1] * scale, 0.f);
        float r2 = fmaxf(v[2] * scale, 0.f), r3 = fmaxf(v[3] * scale, 0.f);
        float r4 = fmaxf(v[4] * scale, 0.f), r5 = fmaxf(v[5] * scale, 0.f);
        float r6 = fmaxf(v[6] * scale, 0.f), r7 = fmaxf(v[7] * scale, 0.f);
        o.x = packbf(r0, r1); o.y = packbf(r2, r3);
        o.z = packbf(r4, r5); o.w = packbf(r6, r7);
        *(uint4*)(xnext + (size_t)node * 512 + lane * 8) = o;
    }
}

// ---------------------------------------------------------------------------
extern "C" void kernel_launch(void* const* d_in, const int* in_sizes, int n_in,
                              void* d_out, int out_size, void* d_ws, size_t ws_size,
                              hipStream_t stream) {
    const float* x    = (const float*)d_in[0];
    const int*   edge = (const int*)d_in[1];     // [2, E]: src row then dst row
    const float* Wl0  = (const float*)d_in[2];
    const float* b0   = (const float*)d_in[3];
    const float* Wr0  = (const float*)d_in[4];
    const float* Wl1  = (const float*)d_in[5];
    const float* b1   = (const float*)d_in[6];
    const float* Wr1  = (const float*)d_in[7];
    const float* Wl2  = (const float*)d_in[8];
    const float* b2   = (const float*)d_in[9];
    const float* Wr2  = (const float*)d_in[10];

    const int E = in_sizes[1] / 2;

    // Workspace layout (bytes), all 256-aligned
    char* ws = (char*)d_ws;
    int*    counts  = (int*)(ws + 0);              // 40000
    int*    offsets = (int*)(ws + 40960);
    int*    cursor  = (int*)(ws + 81920);
    float*  invc    = (float*)(ws + 122880);
    int*    sorted  = (int*)(ws + 163840);         // padded: <=230000*4 = 920000
    ushort* Wc0     = (ushort*)(ws + 1085440);     // 1024*512*2 = 1048576
    ushort* Wc1     = (ushort*)(ws + 2134016);     // 1048576
    ushort* Wc2     = (ushort*)(ws + 3182592);     //  512*512*2 = 524288
    ushort* xbuf    = (ushort*)(ws + 3706880);     // 10000*512*2 = 10240000
    ushort* Gbuf    = (ushort*)(ws + 13946880);    // 10001*512*2 (incl pad row)
    ushort* G2      = (ushort*)(ws + 24188928);    // 10001*256*2 (incl pad row)
    float*  Rbuf    = (float*)(ws + 29309952);     // 10000*512*4 = 20480000
    // end: 49789952 bytes

    // ---- CSR build (8-padded with zero-row index NN) ----
    zero_int<<<(NN + 255) / 256, 256, 0, stream>>>(counts, NN);
    count_dst<<<(E + 255) / 256, 256, 0, stream>>>(edge + E, counts, E);
    scan_build<<<1, 1024, 0, stream>>>(counts, offsets, cursor, invc, sorted, NN);
    scatter_edges<<<(E + 255) / 256, 256, 0, stream>>>(edge, edge + E, cursor, sorted, E);

    // ---- bf16 conversions + pad-row zeroing (single fused launch) ----
    cvt_all<<<(1607776 + 255) / 256, 256, 0, stream>>>(x, Wl0, Wr0, Wl1, Wr1, Wl2, Wr2,
                                                       xbuf, Wc0, Wc1, Wc2, Gbuf, G2);

    const int gyM = (NN + 127) / 128;   // 79
    const int gb  = (NN + 3) / 4;       // 2500

    // ---- layer 0: G|R = x @ [Wl0;Wr0]^T, then gather-mean(G)+R+b0, norm, relu
    gemm_split<<<dim3(8, gyM), 256, 0, stream>>>(xbuf, Wc0, Gbuf, Rbuf, NN, 512);
    aggfin<512, false><<<gb, 256, 0, stream>>>(Gbuf, Rbuf, b0, offsets, counts,
                                               sorted, invc, xbuf, nullptr, NN);
    // ---- layer 1 ----
    gemm_split<<<dim3(8, gyM), 256, 0, stream>>>(xbuf, Wc1, Gbuf, Rbuf, NN, 512);
    aggfin<512, false><<<gb, 256, 0, stream>>>(Gbuf, Rbuf, b1, offsets, counts,
                                               sorted, invc, xbuf, nullptr, NN);
    // ---- layer 2 (dout=256, separate G2 so its pad row isn't clobbered) ----
    gemm_split<<<dim3(4, gyM), 256, 0, stream>>>(xbuf, Wc2, G2, Rbuf, NN, 256);
    aggfin<256, true><<<gb, 256, 0, stream>>>(G2, Rbuf, b2, offsets, counts,
                                              sorted, invc, nullptr, (float*)d_out, NN);
}

// Round 4
// 248.714 us; speedup vs baseline: 1.0310x; 1.0310x over previous
//
#include <hip/hip_runtime.h>

#define NN 10000      // nodes

typedef __attribute__((ext_vector_type(8))) short short8;
typedef __attribute__((ext_vector_type(4))) float f32x4;
typedef __attribute__((ext_vector_type(8))) _Float16 h16x8;
typedef __attribute__((ext_vector_type(4))) _Float16 h16x4;

__device__ __forceinline__ ushort f2b(float f) {
    union { float f; uint32_t u; } v; v.f = f;
    uint32_t u = v.u;
    return (ushort)((u + 0x7fffu + ((u >> 16) & 1u)) >> 16);
}
__device__ __forceinline__ uint packbf(float a, float b) {
    return (uint)f2b(a) | ((uint)f2b(b) << 16);
}
__device__ __forceinline__ float blo(uint u) {
    union { uint u; float f; } v; v.u = u << 16; return v.f;
}
__device__ __forceinline__ float bhi(uint u) {
    union { uint u; float f; } v; v.u = u & 0xffff0000u; return v.f;
}

// ---------------------------------------------------------------------------
// CSR build kernels (R2-proven, padding reverted)
// ---------------------------------------------------------------------------
__global__ __launch_bounds__(256) void count_dst(const int* __restrict__ dst,
                                                 int* __restrict__ counts, int E) {
    int i = blockIdx.x * 256 + threadIdx.x;
    if (i < E) atomicAdd(&counts[dst[i]], 1);
}

__global__ __launch_bounds__(1024) void scan_build(const int* __restrict__ counts,
                                                   int* __restrict__ offsets,
                                                   int* __restrict__ cursor,
                                                   float* __restrict__ inv_cnt, int n) {
    __shared__ int part[1024];
    int tid = threadIdx.x;
    int per = (n + 1023) / 1024;
    int base = tid * per;
    int s = 0;
    for (int i = 0; i < per; i++) { int idx = base + i; if (idx < n) s += counts[idx]; }
    part[tid] = s;
    __syncthreads();
    for (int off = 1; off < 1024; off <<= 1) {
        int v = (tid >= off) ? part[tid - off] : 0;
        __syncthreads();
        part[tid] += v;
        __syncthreads();
    }
    int run = (tid > 0) ? part[tid - 1] : 0;
    for (int i = 0; i < per; i++) {
        int idx = base + i;
        if (idx < n) {
            int c = counts[idx];
            offsets[idx] = run;
            cursor[idx]  = run;
            inv_cnt[idx] = 1.0f / fmaxf((float)c, 1.0f);
            run += c;
        }
    }
}

__global__ __launch_bounds__(256) void scatter_edges(const int* __restrict__ src,
                                                     const int* __restrict__ dst,
                                                     int* __restrict__ cursor,
                                                     int* __restrict__ sorted_src, int E) {
    int i = blockIdx.x * 256 + threadIdx.x;
    if (i < E) {
        int p = atomicAdd(&cursor[dst[i]], 1);
        sorted_src[p] = src[i];
    }
}

// ---------------------------------------------------------------------------
// Single fused fp32->bf16 conversion kernel + counts zeroing (zero_int fused).
// Ranges in 4-element groups:
//   x:  [0, 1280000)          -> xbuf  (linear)
//   W0: [1280000, 1411072)    -> Wc0   (dout=512)
//   W1: [1411072, 1542144)    -> Wc1   (dout=512)
//   W2: [1542144, 1607680)    -> Wc2   (dout=256)
//   [1607680, 1610180): zero counts (2500 thr x int4)
// ---------------------------------------------------------------------------
__global__ __launch_bounds__(256) void cvt_all(const float* __restrict__ x,
                                               const float* __restrict__ Wl0,
                                               const float* __restrict__ Wr0,
                                               const float* __restrict__ Wl1,
                                               const float* __restrict__ Wr1,
                                               const float* __restrict__ Wl2,
                                               const float* __restrict__ Wr2,
                                               ushort* __restrict__ xbuf,
                                               ushort* __restrict__ Wc0,
                                               ushort* __restrict__ Wc1,
                                               ushort* __restrict__ Wc2,
                                               int* __restrict__ counts) {
    int i = blockIdx.x * 256 + threadIdx.x;
    const float* src;
    ushort* dst;
    if (i < 1280000) {
        int idx = i * 4;
        src = x + idx;
        dst = xbuf + idx;
    } else if (i < 1411072) {
        int j = (i - 1280000) * 4;
        int row = j >> 9, col = j & 511;
        src = (row < 512) ? (Wl0 + (size_t)row * 512 + col)
                          : (Wr0 + (size_t)(row - 512) * 512 + col);
        dst = Wc0 + j;
    } else if (i < 1542144) {
        int j = (i - 1411072) * 4;
        int row = j >> 9, col = j & 511;
        src = (row < 512) ? (Wl1 + (size_t)row * 512 + col)
                          : (Wr1 + (size_t)(row - 512) * 512 + col);
        dst = Wc1 + j;
    } else if (i < 1607680) {
        int j = (i - 1542144) * 4;
        int row = j >> 9, col = j & 511;
        src = (row < 256) ? (Wl2 + (size_t)row * 512 + col)
                          : (Wr2 + (size_t)(row - 256) * 512 + col);
        dst = Wc2 + j;
    } else if (i < 1610180) {
        int t = i - 1607680;
        int4 z = {0, 0, 0, 0};
        *(int4*)(counts + t * 4) = z;
        return;
    } else {
        return;
    }
    float4 v = *(const float4*)src;
    uint2 p;
    p.x = packbf(v.x, v.y);
    p.y = packbf(v.z, v.w);
    *(uint2*)dst = p;
}

// ---------------------------------------------------------------------------
// bf16 MFMA NT-GEMM, split output: C[M, 2*dout] = A[M,512] * B[2*dout,512]^T.
// Columns [0,dout) -> G (bf16); [dout,2*dout) -> R (NEW: fp16, halves R traffic).
// Structure otherwise byte-identical to R2 (dbuf 2-phase + XCD swizzle).
// ---------------------------------------------------------------------------
__global__ __launch_bounds__(256) void gemm_split(const ushort* __restrict__ A,
                                                  const ushort* __restrict__ B,
                                                  ushort* __restrict__ G,
                                                  _Float16* __restrict__ R,
                                                  int M, int dout) {
    __shared__ ushort Asl[2][128 * 32];   // 16 KB
    __shared__ ushort Bsl[2][128 * 32];   // 16 KB
    const int tid  = threadIdx.x;
    const int w    = tid >> 6;
    const int lane = tid & 63;

    // --- bijective XCD-chunked swizzle (nwg may not be a multiple of 8) ---
    const int nbx = gridDim.x, nby = gridDim.y;
    const int nwg = nbx * nby;
    const int id  = blockIdx.y * nbx + blockIdx.x;
    const int qq  = nwg >> 3, rr = nwg & 7;
    const int xcd = id & 7, blk = id >> 3;
    const int swzid = (xcd < rr ? xcd * (qq + 1) : rr * (qq + 1) + (xcd - rr) * qq) + blk;
    const int bx = swzid % nbx, by = swzid / nbx;

    const int bm = by * 128, bn = bx * 128;
    const int wm = (w & 1) * 64, wn = (w >> 1) * 64;
    const int row16 = lane & 15, q = lane >> 4;

    f32x4 acc[4][4];
#pragma unroll
    for (int i = 0; i < 4; i++)
#pragma unroll
        for (int j = 0; j < 4; j++) acc[i][j] = (f32x4){0.f, 0.f, 0.f, 0.f};

    const int sc_r = lane >> 2;                  // row within 16-row chunk
    const int sc_s = lane & 3;                   // physical 16B slot
    const int koff = sc_s ^ ((sc_r >> 1) & 3);   // logical k-chunk in this slot
    const int swz  = (row16 >> 1) & 3;

    auto stage = [&](int buf, int k0) {
#pragma unroll
        for (int c = 0; c < 2; c++) {
            int chunk = w * 2 + c;
            int rloc  = chunk * 16 + sc_r;
            int growA = bm + rloc; growA = growA < M ? growA : M - 1;
            const ushort* gpA = A + (size_t)growA * 512 + k0 + koff * 8;
            __builtin_amdgcn_global_load_lds(
                (const __attribute__((address_space(1))) uint32_t*)gpA,
                (__attribute__((address_space(3))) uint32_t*)&Asl[buf][chunk * 512],
                16, 0, 0);
            const ushort* gpB = B + (size_t)(bn + rloc) * 512 + k0 + koff * 8;
            __builtin_amdgcn_global_load_lds(
                (const __attribute__((address_space(1))) uint32_t*)gpB,
                (__attribute__((address_space(3))) uint32_t*)&Bsl[buf][chunk * 512],
                16, 0, 0);
        }
    };

    const int NT = 512 / 32;   // 16 K-steps
    stage(0, 0);
    __syncthreads();
    int cur = 0;

    for (int t = 0; t < NT; ++t) {
        if (t + 1 < NT) stage(cur ^ 1, (t + 1) * 32);

        short8 af[4], bfr[4];
        int s = q ^ swz;
#pragma unroll
        for (int i = 0; i < 4; i++) {
            int r = wm + i * 16 + row16;
            af[i] = *(const short8*)&Asl[cur][r * 32 + s * 8];
        }
#pragma unroll
        for (int j = 0; j < 4; j++) {
            int rn = wn + j * 16 + row16;
            bfr[j] = *(const short8*)&Bsl[cur][rn * 32 + s * 8];
        }
#pragma unroll
        for (int i = 0; i < 4; i++)
#pragma unroll
            for (int j = 0; j < 4; j++)
                acc[i][j] = __builtin_amdgcn_mfma_f32_16x16x32_bf16(
                    af[i], bfr[j], acc[i][j], 0, 0, 0);

        __syncthreads();
        cur ^= 1;
    }

    // C/D layout: col = lane&15, row = (lane>>4)*4 + reg  [m89-verified]
    const bool isR = (bn >= dout);
#pragma unroll
    for (int i = 0; i < 4; i++) {
#pragma unroll
        for (int r2 = 0; r2 < 4; r2++) {
            int row = bm + wm + i * 16 + q * 4 + r2;
            if (row < M) {
                if (isR) {
                    _Float16* Rp = R + (size_t)row * dout + (bn - dout) + wn + row16;
#pragma unroll
                    for (int j = 0; j < 4; j++)
                        Rp[j * 16] = (_Float16)acc[i][j][r2];
                } else {
                    ushort* Gp = G + (size_t)row * dout + bn + wn + row16;
#pragma unroll
                    for (int j = 0; j < 4; j++)
                        Gp[j * 16] = f2b(acc[i][j][r2]);
                }
            }
        }
    }
}

// ---------------------------------------------------------------------------
// Fused neighbor mean + R + bias + L2-normalize + ReLU (R2-proven structure;
// only change: R is fp16 now).
// ---------------------------------------------------------------------------
template <int DOUT, bool FINAL>
__global__ __launch_bounds__(256) void aggfin(const ushort* __restrict__ G,
                                              const _Float16* __restrict__ R,
                                              const float* __restrict__ bias,
                                              const int* __restrict__ offsets,
                                              const int* __restrict__ counts,
                                              const int* __restrict__ sorted_src,
                                              const float* __restrict__ inv_cnt,
                                              ushort* __restrict__ xnext,
                                              float* __restrict__ outf, int n) {
    constexpr int PL = DOUT / 64;    // floats per lane: 8 (512) or 4 (256)
    int wave = threadIdx.x >> 6;
    int lane = threadIdx.x & 63;
    int node = blockIdx.x * 4 + wave;
    if (node >= n) return;
    int start = offsets[node];
    int cnt   = counts[node];
    float inv = inv_cnt[node];

    float acc[PL];
#pragma unroll
    for (int k = 0; k < PL; k++) acc[k] = 0.f;

    if constexpr (DOUT == 512) {
        const uint* gp = (const uint*)G + lane * 4;   // row stride 256 uints
#define ACC8(v) do { \
        acc[0] += blo(v.x); acc[1] += bhi(v.x); \
        acc[2] += blo(v.y); acc[3] += bhi(v.y); \
        acc[4] += blo(v.z); acc[5] += bhi(v.z); \
        acc[6] += blo(v.w); acc[7] += bhi(v.w); } while (0)
        int e = 0;
        for (; e + 8 <= cnt; e += 8) {
            uint4 vv[8];
#pragma unroll
            for (int u = 0; u < 8; u++) {
                int s0 = sorted_src[start + e + u];
                vv[u] = *(const uint4*)(gp + (size_t)s0 * 256);
            }
#pragma unroll
            for (int u = 0; u < 8; u++) ACC8(vv[u]);
        }
        for (; e < cnt; e++) {
            int s0 = sorted_src[start + e];
            uint4 v0 = *(const uint4*)(gp + (size_t)s0 * 256);
            ACC8(v0);
        }
#undef ACC8
    } else {
        const uint* gp = (const uint*)G + lane * 2;   // row stride 128 uints
#define ACC4(v) do { \
        acc[0] += blo(v.x); acc[1] += bhi(v.x); \
        acc[2] += blo(v.y); acc[3] += bhi(v.y); } while (0)
        int e = 0;
        for (; e + 8 <= cnt; e += 8) {
            uint2 vv[8];
#pragma unroll
            for (int u = 0; u < 8; u++) {
                int s0 = sorted_src[start + e + u];
                vv[u] = *(const uint2*)(gp + (size_t)s0 * 128);
            }
#pragma unroll
            for (int u = 0; u < 8; u++) ACC4(vv[u]);
        }
        for (; e < cnt; e++) {
            int s0 = sorted_src[start + e];
            uint2 v0 = *(const uint2*)(gp + (size_t)s0 * 128);
            ACC4(v0);
        }
#undef ACC4
    }

    float v[PL];
    const _Float16* Rp = R + (size_t)node * DOUT + lane * PL;
    const float* Bp = bias + lane * PL;
    if constexpr (PL == 8) {
        h16x8 hv = *(const h16x8*)Rp;
#pragma unroll
        for (int k = 0; k < PL; k += 4) {
            float4 b4 = *(const float4*)(Bp + k);
            v[k + 0] = acc[k + 0] * inv + (float)hv[k + 0] + b4.x;
            v[k + 1] = acc[k + 1] * inv + (float)hv[k + 1] + b4.y;
            v[k + 2] = acc[k + 2] * inv + (float)hv[k + 2] + b4.z;
            v[k + 3] = acc[k + 3] * inv + (float)hv[k + 3] + b4.w;
        }
    } else {
        h16x4 hv = *(const h16x4*)Rp;
#pragma unroll
        for (int k = 0; k < PL; k += 4) {
            float4 b4 = *(const float4*)(Bp + k);
            v[k + 0] = acc[k + 0] * inv + (float)hv[k + 0] + b4.x;
            v[k + 1] = acc[k + 1] * inv + (float)hv[k + 1] + b4.y;
            v[k + 2] = acc[k + 2] * inv + (float)hv[k + 2] + b4.z;
            v[k + 3] = acc[k + 3] * inv + (float)hv[k + 3] + b4.w;
        }
    }

    float ss = 0.f;
#pragma unroll
    for (int k = 0; k < PL; k++) ss += v[k] * v[k];
#pragma unroll
    for (int m = 32; m >= 1; m >>= 1) ss += __shfl_xor(ss, m, 64);
    float scale = 1.0f / fmaxf(sqrtf(ss), 1e-12f);

    if constexpr (FINAL) {
        float* Op = outf + (size_t)node * DOUT + lane * PL;
#pragma unroll
        for (int k = 0; k < PL; k += 4) {
            float4 o;
            o.x = fmaxf(v[k + 0] * scale, 0.f);
            o.y = fmaxf(v[k + 1] * scale, 0.f);
            o.z = fmaxf(v[k + 2] * scale, 0.f);
            o.w = fmaxf(v[k + 3] * scale, 0.f);
            *(float4*)(Op + k) = o;
        }
    } else {
        // DOUT == 512: 8 bf16 = 16B per lane
        uint4 o;
        float r0 = fmaxf(v[0] * scale, 0.f), r1 = fmaxf(v[1] * scale, 0.f);
        float r2 = fmaxf(v[2] * scale, 0.f), r3 = fmaxf(v[3] * scale, 0.f);
        float r4 = fmaxf(v[4] * scale, 0.f), r5 = fmaxf(v[5] * scale, 0.f);
        float r6 = fmaxf(v[6] * scale, 0.f), r7 = fmaxf(v[7] * scale, 0.f);
        o.x = packbf(r0, r1); o.y = packbf(r2, r3);
        o.z = packbf(r4, r5); o.w = packbf(r6, r7);
        *(uint4*)(xnext + (size_t)node * 512 + lane * 8) = o;
    }
}

// ---------------------------------------------------------------------------
extern "C" void kernel_launch(void* const* d_in, const int* in_sizes, int n_in,
                              void* d_out, int out_size, void* d_ws, size_t ws_size,
                              hipStream_t stream) {
    const float* x    = (const float*)d_in[0];
    const int*   edge = (const int*)d_in[1];     // [2, E]: src row then dst row
    const float* Wl0  = (const float*)d_in[2];
    const float* b0   = (const float*)d_in[3];
    const float* Wr0  = (const float*)d_in[4];
    const float* Wl1  = (const float*)d_in[5];
    const float* b1   = (const float*)d_in[6];
    const float* Wr1  = (const float*)d_in[7];
    const float* Wl2  = (const float*)d_in[8];
    const float* b2   = (const float*)d_in[9];
    const float* Wr2  = (const float*)d_in[10];

    const int E = in_sizes[1] / 2;

    // Workspace layout (bytes), all 256-aligned
    char* ws = (char*)d_ws;
    int*      counts  = (int*)(ws + 0);              // 40000
    int*      offsets = (int*)(ws + 40960);
    int*      cursor  = (int*)(ws + 81920);
    float*    invc    = (float*)(ws + 122880);
    int*      sorted  = (int*)(ws + 163840);         // 640000
    ushort*   Wc0     = (ushort*)(ws + 819200);      // 1024*512*2 = 1048576
    ushort*   Wc1     = (ushort*)(ws + 1867776);     // 1048576
    ushort*   Wc2     = (ushort*)(ws + 2916352);     //  512*512*2 = 524288
    ushort*   xbuf    = (ushort*)(ws + 3440640);     // 10000*512*2 = 10240000
    ushort*   Gbuf    = (ushort*)(ws + 13680640);    // 10000*512*2 = 10240000
    _Float16* Rbuf    = (_Float16*)(ws + 23920640);  // 10000*512*2 = 10240000
    // end: 34160640 bytes

    // ---- bf16 conversions + counts zeroing (single fused launch, first) ----
    cvt_all<<<(1610180 + 255) / 256, 256, 0, stream>>>(x, Wl0, Wr0, Wl1, Wr1, Wl2, Wr2,
                                                       xbuf, Wc0, Wc1, Wc2, counts);

    // ---- CSR build ----
    count_dst<<<(E + 255) / 256, 256, 0, stream>>>(edge + E, counts, E);
    scan_build<<<1, 1024, 0, stream>>>(counts, offsets, cursor, invc, NN);
    scatter_edges<<<(E + 255) / 256, 256, 0, stream>>>(edge, edge + E, cursor, sorted, E);

    const int gyM = (NN + 127) / 128;   // 79
    const int gb  = (NN + 3) / 4;       // 2500

    // ---- layer 0: G|R = x @ [Wl0;Wr0]^T, then gather-mean(G)+R+b0, norm, relu
    gemm_split<<<dim3(8, gyM), 256, 0, stream>>>(xbuf, Wc0, Gbuf, Rbuf, NN, 512);
    aggfin<512, false><<<gb, 256, 0, stream>>>(Gbuf, Rbuf, b0, offsets, counts,
                                               sorted, invc, xbuf, nullptr, NN);
    // ---- layer 1 ----
    gemm_split<<<dim3(8, gyM), 256, 0, stream>>>(xbuf, Wc1, Gbuf, Rbuf, NN, 512);
    aggfin<512, false><<<gb, 256, 0, stream>>>(Gbuf, Rbuf, b1, offsets, counts,
                                               sorted, invc, xbuf, nullptr, NN);
    // ---- layer 2 (dout=256, final fp32 out) ----
    gemm_split<<<dim3(4, gyM), 256, 0, stream>>>(xbuf, Wc2, Gbuf, Rbuf, NN, 256);
    aggfin<256, true><<<gb, 256, 0, stream>>>(Gbuf, Rbuf, b2, offsets, counts,
                                              sorted, invc, nullptr, (float*)d_out, NN);
}